// Round 5
// baseline (29.992 us; speedup 1.0000x reference)
//
#include <hip/hip_runtime.h>

// TensorSketch, frequency domain + coefficient-free parallel scan + packed math.
// d_p = Tp[p]-Tm[p]: d_p <- (1-z)d_p + z*sigma*w(k)*d_{p-1}, w(k)=e^{+2pi i r k/D}.
// Substitution d_p(i) = h_p(i)/binom(i+1,p) cancels all coefficients:
//     h_p(i) = h_p(i-1) + w_p[ch_i] * h_{p-1}(i-1),  h_0 == 1
// Chunk transfer U is UNIT lower-triangular (6 complex entries). Complex state
// kept as float2 -> v_pk_fma_f32 (dual fp32 FMA): 9 packed instrs/step.
// Conjugate symmetry: k=0..512 only; k=512 real. Output = Re(IDFT(d3)), IDFT
// via per-thread incremental rotator (no trig in inner loop).

typedef float f32x2 __attribute__((ext_vector_type(2)));

constexpr int DD = 1024;
constexpr int L_FIX = 1024;
constexpr int NCH = 16;      // chunks (waves) per scan block
constexpr int CHUNK = 64;    // steps per chunk
constexpr float INV_D = 1.0f / 1024.0f;
// 1 / (binom(1024,3) * D) -- folds IDFT 1/D and the h->d scaling (exact fp32)
constexpr float OUT_SCALE = (float)(1.0 / (178433024.0 * 1024.0));

__device__ __forceinline__ float fcosr(float rev) {   // cos(2*pi*rev)
#if __has_builtin(__builtin_amdgcn_cosf)
    return __builtin_amdgcn_cosf(rev);
#else
    return __cosf(rev * 6.283185307f);
#endif
}
__device__ __forceinline__ float fsinr(float rev) {   // sin(2*pi*rev)
#if __has_builtin(__builtin_amdgcn_sinf)
    return __builtin_amdgcn_sinf(rev);
#else
    return __sinf(rev * 6.283185307f);
#endif
}

// acc + w*v (complex). (-v.y, v.x) folds into VOP3P op_sel/neg -> 2 v_pk_fma_f32.
__device__ __forceinline__ f32x2 cfma(f32x2 w, f32x2 v, f32x2 acc) {
    f32x2 vp = { -v.y, v.x };
    acc += ((f32x2){w.x, w.x}) * v;
    acc += ((f32x2){w.y, w.y}) * vp;
    return acc;
}

__global__ __launch_bounds__(1024) void sketch_scan(
    const int* __restrict__ seq,
    const int* __restrict__ hash_t,
    const void* __restrict__ sign_raw,
    float2* __restrict__ d3out)
{
    const int blk = blockIdx.x;            // B * 8
    const int b = blk >> 3, kblk = blk & 7;
    const int tid = (int)threadIdx.x;
    const int lane = tid & 63;
    const int c = tid >> 6;                // chunk id 0..15 (wave-uniform)
    const int k = (kblk << 6) + lane;      // frequency bin 0..511

    __shared__ int s_seq[L_FIX];
    __shared__ f32x2 sP[6 * NCH * 64];     // [entry][chunk*64+lane], 48 KiB

    s_seq[tid] = seq[b * L_FIX + tid];

    // sign table layout detect (int32 {0,1} vs packed bytes) - verified r2
    const unsigned* sW = (const unsigned*)sign_raw;
    const int* sIt = (const int*)sign_raw;
    const unsigned char* sBt = (const unsigned char*)sign_raw;
    const bool i32lay = (sW[0] <= 1u) && (sW[1] <= 1u) && (sW[2] <= 1u);

    // wl_p[ch] = sigma * e^{+2 pi i r k / D}; angle exactly m/1024 revolutions
    f32x2 wl1[4], wl2[4], wl3[4];
#pragma unroll
    for (int l = 0; l < 3; ++l) {
#pragma unroll
        for (int ch = 0; ch < 4; ++ch) {
            int r = hash_t[l * 4 + ch];
            int sv = i32lay ? sIt[l * 4 + ch] : (int)sBt[l * 4 + ch];
            float sg = sv ? 1.0f : -1.0f;
            float rev = (float)((r * k) & (DD - 1)) * INV_D;
            f32x2 w = { sg * fcosr(rev), sg * fsinr(rev) };
            if (l == 0)      wl1[ch] = w;
            else if (l == 1) wl2[ch] = w;
            else             wl3[ch] = w;
        }
    }
    __syncthreads();

    f32x2 U10 = {0.f,0.f}, U20 = {0.f,0.f}, U21 = {0.f,0.f};
    f32x2 U30 = {0.f,0.f}, U31 = {0.f,0.f}, U32 = {0.f,0.f};

    // U <- N_i * U; rows 3,2 read OLD lower rows (descending update order)
#define CORE(CH) do { \
        U30 = cfma(wl3[CH], U20, U30); \
        U31 = cfma(wl3[CH], U21, U31); \
        U32 += wl3[CH]; \
        U20 = cfma(wl2[CH], U10, U20); \
        U21 += wl2[CH]; \
        U10 += wl1[CH]; \
    } while (0)
#define STEP(CV) do { \
        int cv_ = __builtin_amdgcn_readfirstlane(CV) & 3; \
        switch (cv_) { \
            case 0: CORE(0); break; \
            case 1: CORE(1); break; \
            case 2: CORE(2); break; \
            default: CORE(3); break; \
        } \
    } while (0)

    const int g0 = c * CHUNK;
    int4 nxt = *(const int4*)&s_seq[g0];
    for (int s = 0; s < CHUNK; s += 4) {
        int4 cur = nxt;
        if (s + 4 < CHUNK) nxt = *(const int4*)&s_seq[g0 + s + 4];
        STEP(cur.x); STEP(cur.y); STEP(cur.z); STEP(cur.w);
    }
#undef STEP
#undef CORE

    {   // [entry][chunk*64+lane]
        const int base = c * 64 + lane;
        sP[0*1024 + base] = U10;
        sP[1*1024 + base] = U20;
        sP[2*1024 + base] = U21;
        sP[3*1024 + base] = U30;
        sP[4*1024 + base] = U31;
        sP[5*1024 + base] = U32;
    }
    __syncthreads();

    // combine: h = U_15 ... U_0 * (1,0,0,0); unit diag -> v_p accumulates
    if (c == 0) {
        f32x2 v1 = {0.f,0.f}, v2 = {0.f,0.f}, v3 = {0.f,0.f};
#pragma unroll 4
        for (int q = 0; q < NCH; ++q) {
            const f32x2* M = &sP[q * 64 + lane];
            f32x2 m10 = M[0*1024], m20 = M[1*1024], m21 = M[2*1024];
            f32x2 m30 = M[3*1024], m31 = M[4*1024], m32 = M[5*1024];
            f32x2 nv3 = v3 + m30;
            nv3 = cfma(m31, v1, nv3);
            nv3 = cfma(m32, v2, nv3);
            f32x2 nv2 = v2 + m20;
            nv2 = cfma(m21, v1, nv2);
            v1 += m10;
            v3 = nv3; v2 = nv2;
        }
        // conj-pair IDFT weight: k=0 -> 1, k>=1 -> 2 (all /(D*binom))
        float scale = (k == 0) ? OUT_SCALE : 2.0f * OUT_SCALE;
        d3out[b * 576 + k] = make_float2(v3.x * scale, v3.y * scale);
    }

    // k = 512: w real (= sigma*(-1)^r). 64 lanes x 16 steps, then butterfly
    // compose (non-commutative: lane with bit set holds the LATER half).
    if (c == 1 && kblk == 0) {
        float q1[4], q2[4], q3[4];
#pragma unroll
        for (int l = 0; l < 3; ++l) {
#pragma unroll
            for (int ch = 0; ch < 4; ++ch) {
                int r = hash_t[l * 4 + ch];
                int sv = i32lay ? sIt[l * 4 + ch] : (int)sBt[l * 4 + ch];
                float sg = sv ? 1.0f : -1.0f;
                float w = (r & 1) ? -sg : sg;
                if (l == 0) q1[ch] = w; else if (l == 1) q2[ch] = w; else q3[ch] = w;
            }
        }
        float Q10=0.f,Q20=0.f,Q21=0.f,Q30=0.f,Q31=0.f,Q32=0.f;
        const int g = lane * 16;
        for (int s = 0; s < 16; ++s) {
            int cq = s_seq[g + s] & 3;
            float a1 = (cq==0)?q1[0]:(cq==1)?q1[1]:(cq==2)?q1[2]:q1[3];
            float a2 = (cq==0)?q2[0]:(cq==1)?q2[1]:(cq==2)?q2[2]:q2[3];
            float a3 = (cq==0)?q3[0]:(cq==1)?q3[1]:(cq==2)?q3[2]:q3[3];
            Q30 += a3 * Q20; Q31 += a3 * Q21; Q32 += a3;
            Q20 += a2 * Q10; Q21 += a2;
            Q10 += a1;
        }
#pragma unroll
        for (int m = 0; m < 6; ++m) {
            int bit = (lane >> m) & 1;
            float p10 = __shfl_xor(Q10, 1 << m, 64);
            float p20 = __shfl_xor(Q20, 1 << m, 64);
            float p21 = __shfl_xor(Q21, 1 << m, 64);
            float p30 = __shfl_xor(Q30, 1 << m, 64);
            float p31 = __shfl_xor(Q31, 1 << m, 64);
            float p32 = __shfl_xor(Q32, 1 << m, 64);
            float B10 = bit ? Q10 : p10, A10 = bit ? p10 : Q10;
            float B20 = bit ? Q20 : p20, A20 = bit ? p20 : Q20;
            float B21 = bit ? Q21 : p21, A21 = bit ? p21 : Q21;
            float B30 = bit ? Q30 : p30, A30 = bit ? p30 : Q30;
            float B31 = bit ? Q31 : p31, A31 = bit ? p31 : Q31;
            float B32 = bit ? Q32 : p32, A32 = bit ? p32 : Q32;
            Q10 = B10 + A10;
            Q21 = B21 + A21;
            Q32 = B32 + A32;
            Q20 = B20 + A20 + B21 * A10;
            Q31 = B31 + A31 + B32 * A21;
            Q30 = B30 + A30 + B31 * A10 + B32 * A20;
        }
        if (lane == 0)
            d3out[b * 576 + 512] = make_float2(Q30 * OUT_SCALE, 0.0f);
    }
}

// out[j]     = F'(0) + sum_{k=1..512} F'r cos(2pi jk/D) - F'i sin(2pi jk/D)
// out[j+512] = same with (-1)^k.  Per-thread incremental rotator:
// R_{k+1} = R_k * e^{+2 pi i j / D}; term = (F*R).x - (F*R).y via packed FMA.
__global__ __launch_bounds__(512) void idft_sym(
    const float2* __restrict__ d3, float* __restrict__ out)
{
    const int blk = blockIdx.x;          // B * 8
    const int b = blk >> 3, jb = blk & 7;
    const int tid = (int)threadIdx.x;
    const int lane = tid & 63, q = tid >> 6;   // k-slice 0..7
    const int j = (jb << 6) + lane;            // 0..511

    __shared__ f32x2 sF[513];
    __shared__ float sE_[8 * 64], sO_[8 * 64];
    for (int i = tid; i < 513; i += 512) {
        float2 t = d3[b * 576 + i];
        sF[i] = (f32x2){t.x, t.y};
    }
    __syncthreads();

    const int k0 = 1 + (q << 6);         // odd start; slice covers k0..k0+63
    int m0 = (j * k0) & (DD - 1);
    f32x2 R = { fcosr((float)m0 * INV_D), fsinr((float)m0 * INV_D) };
    f32x2 E = { fcosr((float)j * INV_D),  fsinr((float)j * INV_D) };
    const f32x2 Z = {0.f, 0.f};

    f32x2 accO = Z, accE = Z;            // packed partial products (x: Fr*c, y: Fi*s)
    const f32x2* Fp = &sF[k0];
#pragma unroll 8
    for (int t2 = 0; t2 < 64; t2 += 2) {
        accO += Fp[t2] * R;              // odd k
        R = cfma(E, R, Z);               // advance rotator
        accE += Fp[t2 + 1] * R;          // even k
        R = cfma(E, R, Z);
    }
    sE_[q * 64 + lane] = accE.x - accE.y;
    sO_[q * 64 + lane] = accO.x - accO.y;
    __syncthreads();

    if (q == 0) {
        float e = sF[0].x, o = 0.f;
#pragma unroll
        for (int qq = 0; qq < 8; ++qq) {
            e += sE_[qq * 64 + lane];
            o += sO_[qq * 64 + lane];
        }
        out[b * DD + j]       = e + o;
        out[b * DD + j + 512] = e - o;
    }
}

extern "C" void kernel_launch(void* const* d_in, const int* in_sizes, int n_in,
                              void* d_out, int out_size, void* d_ws, size_t ws_size,
                              hipStream_t stream) {
    const int* seq = (const int*)d_in[0];
    const int* hash_t = (const int*)d_in[1];
    const void* sign_t = (const void*)d_in[2];
    // d_in[3]/d_in[4] (Tp0/Tm0): fixed e0 pattern folded into h_0 == 1.

    const int B = in_sizes[0] / L_FIX;   // 32

    float2* d3buf = (float2*)d_ws;       // B x 576 complex = 147 KiB
    float* outp = (float*)d_out;

    sketch_scan<<<B * 8, 1024, 0, stream>>>(seq, hash_t, sign_t, d3buf);
    idft_sym<<<B * 8, 512, 0, stream>>>(d3buf, outp);
}

// Round 6
// 13.009 us; speedup vs baseline: 2.3055x; 2.3055x over previous
//
#include <hip/hip_runtime.h>

// TensorSketch — closed form. Unrolling the recurrence with operators
// w_p[ch] = sigma_p[ch] * CircShift_{r_p[ch]} (which commute) gives
//   h3 = sum_{i1<i2<i3} w1[c_i1] w2[c_i2] w3[c_i3] e_0
// Circular shifts compose additively, so grouping by character-value triple:
//   out[b][j] = scale * sum_{(A,B,C) in 4^3} V_ABC * sg1[C]sg2[B]sg3[A]
//                       * [ j == (D - (r1[C]+r2[B]+r3[A])) mod D ]
// with V_ABC = #{i1<i2<i3: c_i1=C, c_i2=B, c_i3=A} (ordered-triple counts,
// int32-exact, <= binom(1024,3)=1.78e8) and scale = 1/binom(L,3).
// Invalid chars (outside [0,4)) match no pattern -> identity, as in reference.
//
// One kernel, one block per batch: 16 waves count 64-position chunks
// (lane = pattern; char is wave-uniform -> 3 compare-accumulates/position),
// unit-triangular chunk combine, deterministic scatter via match-accumulate.

constexpr int DD = 1024;

__global__ __launch_bounds__(1024) void sketch_count(
    const int* __restrict__ seq,
    const int* __restrict__ hash_t,
    const void* __restrict__ sign_raw,
    float* __restrict__ out, int L, float scale)
{
    const int b = blockIdx.x;
    const int tid = (int)threadIdx.x;
    const int lane = tid & 63;
    const int w = tid >> 6;                 // wave id = chunk id, 0..15

    __shared__ int   s_seq[DD];
    __shared__ int   sN[16][64][3];         // per-chunk (n1,n2,n3) per pattern
    __shared__ int   sJ[64];
    __shared__ float sV[64];

    for (int i = tid; i < L; i += 1024)
        s_seq[i] = seq[b * L + i];

    // pattern of this lane: chars (C at i1, B at i2, A at i3)
    const int A = (lane >> 4) & 3, B = (lane >> 2) & 3, C = lane & 3;

    // ---- scatter target & sign for this pattern (prefetched early; only
    // wave 0's values are used). sign layout detect as verified in r2. ----
    const unsigned* sWd = (const unsigned*)sign_raw;
    const int* sIt = (const int*)sign_raw;
    const unsigned char* sBt = (const unsigned char*)sign_raw;
    const bool i32lay = (sWd[0] <= 1u) && (sWd[1] <= 1u) && (sWd[2] <= 1u);
    const int r1h = hash_t[0 * 4 + C];
    const int r2h = hash_t[1 * 4 + B];
    const int r3h = hash_t[2 * 4 + A];
    const int sv1 = i32lay ? sIt[0 * 4 + C] : (int)sBt[0 * 4 + C];
    const int sv2 = i32lay ? sIt[1 * 4 + B] : (int)sBt[1 * 4 + B];
    const int sv3 = i32lay ? sIt[2 * 4 + A] : (int)sBt[2 * 4 + A];
    const int jt = (DD - ((r1h + r2h + r3h) & (DD - 1))) & (DD - 1);
    // sigma = +1 if sign true else -1; product via XOR of "false" flags
    const int neg = (sv1 == 0) ^ (sv2 == 0) ^ (sv3 == 0);
    const float sg = neg ? -1.0f : 1.0f;

    __syncthreads();

    // ---- count phase: this wave's chunk, descending-order updates ----
    int n1 = 0, n2 = 0, n3 = 0;
    const int chunk = L >> 4;               // 64
    const int g0 = w * chunk;
#define POSSTEP(XV) do { \
        int x_ = __builtin_amdgcn_readfirstlane(XV); \
        n3 += (x_ == A) ? n2 : 0; \
        n2 += (x_ == B) ? n1 : 0; \
        n1 += (x_ == C) ? 1 : 0; \
    } while (0)
    for (int s = 0; s < chunk; s += 4) {
        int4 cs = *(const int4*)&s_seq[g0 + s];
        POSSTEP(cs.x); POSSTEP(cs.y); POSSTEP(cs.z); POSSTEP(cs.w);
    }
#undef POSSTEP
    sN[w][lane][0] = n1; sN[w][lane][1] = n2; sN[w][lane][2] = n3;
    __syncthreads();

    // ---- combine 16 chunks in position order (prefix N, append chunk q):
    //  N3 += n3_q + N2*cntA_q + N1*pairsBA_q ;  N2 += n2_q + N1*cntB_q ;
    //  N1 += n1_q.  cnt_x(q) = n1 of pattern lane x; pairs(B then A) = n2 of
    //  pattern lane (A<<2)|B.  Overflow bound: N2*cntA <= 5.3e5*64 = 3.4e7. ----
    if (w == 0) {
        const int lBA = (A << 2) | B;
        int N1 = 0, N2 = 0, N3 = 0;
#pragma unroll
        for (int q = 0; q < 16; ++q) {
            int r1 = sN[q][lane][0], r2 = sN[q][lane][1], r3 = sN[q][lane][2];
            int cA  = sN[q][A][0];
            int cB  = sN[q][B][0];
            int pBA = sN[q][lBA][1];
            N3 += r3 + N2 * cA + N1 * pBA;
            N2 += r2 + N1 * cB;
            N1 += r1;
        }
        sJ[lane] = jt;
        sV[lane] = sg * (float)N3 * scale;
    }
    __syncthreads();

    // ---- deterministic scatter: fixed-order match-accumulate ----
    for (int j = tid; j < DD; j += 1024) {
        float acc = 0.0f;
#pragma unroll
        for (int t = 0; t < 64; ++t)
            acc += (sJ[t] == j) ? sV[t] : 0.0f;
        out[b * DD + j] = acc;
    }
}

extern "C" void kernel_launch(void* const* d_in, const int* in_sizes, int n_in,
                              void* d_out, int out_size, void* d_ws, size_t ws_size,
                              hipStream_t stream) {
    const int* seq = (const int*)d_in[0];
    const int* hash_t = (const int*)d_in[1];
    const void* sign_t = (const void*)d_in[2];
    // d_in[3]/d_in[4] (Tp0/Tm0): fixed e0 pattern -> h_0 == 1, folded in.

    const int B = out_size / DD;                 // 32
    const int L = in_sizes[0] / B;               // 1024
    const float scale = (float)(6.0 / ((double)L * (double)(L - 1) * (double)(L - 2)));

    sketch_count<<<B, 1024, 0, stream>>>(seq, hash_t, sign_t,
                                         (float*)d_out, L, scale);
}